// Round 8
// baseline (219.339 us; speedup 1.0000x reference)
//
#include <hip/hip_runtime.h>

// PiecewiseDiscontinuousPolynomial — R8 = R7 DIAGNOSTIC (resubmit; infra died)
// Evidence so far: our kernels never crack the top-5 (all fills ~41us),
// so main < 41us, and dur_us=115 must include ~70us harness reset floor.
// No counters for our kernels are visible. This round: repeat main's body
// REP=8x in ONE dispatch (idempotent: same out written each rep) so
// pdp_main tops the profile table WITH counters. T_main = dispatch_dur/8.
// Next round reverts REP=1 and applies whatever the counters indicate.

#define IN_F  256
#define NW    40960   // w leading dimension (columns)
#define NSEG  32
#define NNODE 5
#define USED_COLS (NSEG * NNODE)   // 160

typedef float f32x4 __attribute__((ext_vector_type(4)));

__global__ __launch_bounds__(256) void pdp_prep(const float* __restrict__ w,
                                                float* __restrict__ wt) {
    int tid = blockIdx.x * blockDim.x + threadIdx.x;
    if (tid >= USED_COLS * IN_F) return;
    int f = tid / USED_COLS;   // 0..255
    int c = tid % USED_COLS;   // 0..159  (reads contiguous in c per f)
    int j = c % NNODE;
    // c_j = 1 / prod_{m!=j}(X_j - X_m),  X = {-1,-0.5,0,0.5,1}
    float cj = (j == 2) ? 4.0f : ((j == 1 || j == 3) ? (-8.0f / 3.0f) : (2.0f / 3.0f));
    wt[c * IN_F + f] = w[(size_t)f * NW + c] * cj;
}

__device__ __forceinline__ float pdp_eval(float xe,
                                          float w0, float w1, float w2,
                                          float w3, float w4) {
    // bitwise == reference: all scalings are exact powers of two
    float idf  = floorf((xe + 1.0f) * 16.0f);        // == floor((x+1)/2*32)
    float xmin = idf * 0.0625f - 1.0f;               // exact
    float xin  = (xe - xmin) * 32.0f - 1.0f;         // exact

    float t0 = xin + 1.0f;
    float t1 = xin + 0.5f;
    float t2 = xin;
    float t3 = xin - 0.5f;
    float t4 = xin - 1.0f;

    // numerators via prefix/suffix products (denominators folded into w)
    float p1 = t0;
    float p2 = p1 * t1;
    float p3 = p2 * t2;
    float p4 = p3 * t3;
    float s3 = t4;
    float s2 = s3 * t3;
    float s1 = s2 * t2;
    float s0 = s1 * t1;

    float fx = s0 * w0;
    fx = fmaf(p1 * s1, w1, fx);
    fx = fmaf(p2 * s2, w2, fx);
    fx = fmaf(p3 * s3, w3, fx);
    fx = fmaf(p4,      w4, fx);
    return fx;
}

template <bool TR, int REP>
__global__ __launch_bounds__(256) void pdp_main(const float* __restrict__ x,
                                                const float* __restrict__ wsrc,
                                                float* __restrict__ out,
                                                int rows) {
    const int lane   = threadIdx.x & 63;
    const int wv     = threadIdx.x >> 6;   // 4 waves/block -> 4 rows/iter
    const int f0     = lane << 2;          // this lane's first feature
    const int stride = gridDim.x * 4;
    const int b0     = blockIdx.x * 4 + wv;

    if (b0 >= rows) return;

#pragma unroll 1
    for (int rep = 0; rep < REP; ++rep) {
        int b = b0;
        // pipeline prologue: first x load
        f32x4 xv = __builtin_nontemporal_load(
            reinterpret_cast<const f32x4*>(x + (size_t)b * IN_F + f0));

        while (true) {
            // issue next iteration's x load BEFORE consuming xv (uniform branch)
            const int bn = b + stride;
            const bool have_next = bn < rows;
            f32x4 xn;
            if (have_next)
                xn = __builtin_nontemporal_load(
                    reinterpret_cast<const f32x4*>(x + (size_t)bn * IN_F + f0));

            // row segment from feature 0 (lane 0 holds it) -- wave-uniform
            float x0  = __shfl(xv.x, 0);
            int   seg = (int)floorf((x0 + 1.0f) * 16.0f);

            float wf[NNODE][4];
            if constexpr (TR) {
                // coalesced: wt[(seg*5+j)*256 + f], prescaled by c_j
                const float* p = wsrc + (size_t)(seg * NNODE) * IN_F + f0;
#pragma unroll
                for (int j = 0; j < NNODE; ++j) {
                    f32x4 t = *reinterpret_cast<const f32x4*>(p + j * IN_F);
                    wf[j][0] = t.x; wf[j][1] = t.y; wf[j][2] = t.z; wf[j][3] = t.w;
                }
            } else {
                const float C0 = 2.0f / 3.0f, C1 = -8.0f / 3.0f, C2 = 4.0f;
#pragma unroll
                for (int fi = 0; fi < 4; ++fi) {
                    const float* p = wsrc + (size_t)(f0 + fi) * NW + seg * NNODE;
                    wf[0][fi] = p[0] * C0;
                    wf[1][fi] = p[1] * C1;
                    wf[2][fi] = p[2] * C2;
                    wf[3][fi] = p[3] * C1;
                    wf[4][fi] = p[4] * C0;
                }
            }

            f32x4 o;
            o.x = pdp_eval(xv.x, wf[0][0], wf[1][0], wf[2][0], wf[3][0], wf[4][0]);
            o.y = pdp_eval(xv.y, wf[0][1], wf[1][1], wf[2][1], wf[3][1], wf[4][1]);
            o.z = pdp_eval(xv.z, wf[0][2], wf[1][2], wf[2][2], wf[3][2], wf[4][2]);
            o.w = pdp_eval(xv.w, wf[0][3], wf[1][3], wf[2][3], wf[3][3], wf[4][3]);

            __builtin_nontemporal_store(
                o, reinterpret_cast<f32x4*>(out + (size_t)b * IN_F + f0));

            if (!have_next) break;
            xv = xn;
            b  = bn;
        }
    }
}

extern "C" void kernel_launch(void* const* d_in, const int* in_sizes, int n_in,
                              void* d_out, int out_size, void* d_ws, size_t ws_size,
                              hipStream_t stream) {
    const float* x = (const float*)d_in[0];
    const float* w = (const float*)d_in[1];
    float* out = (float*)d_out;

    const int B = in_sizes[0] / IN_F;   // 32768

    // grid: cap ~2048 blocks, grid-stride over rows (4 rows per block-iter)
    int nblk = (B + 3) / 4;
    if (nblk > 2048) nblk = 2048;

    const size_t wt_bytes = (size_t)USED_COLS * IN_F * sizeof(float);  // 160 KB
    if (ws_size >= wt_bytes) {
        float* wt = (float*)d_ws;
        const int total = USED_COLS * IN_F;
        pdp_prep<<<(total + 255) / 256, 256, 0, stream>>>(w, wt);
        pdp_main<true, 8><<<nblk, 256, 0, stream>>>(x, wt, out, B);
    } else {
        pdp_main<false, 8><<<nblk, 256, 0, stream>>>(x, w, out, B);
    }
}

// Round 9
// 116.135 us; speedup vs baseline: 1.8887x; 1.8887x over previous
//
#include <hip/hip_runtime.h>

// PiecewiseDiscontinuousPolynomial — R9: 3-stage software pipeline
// R8 diagnostic (REP=8) counters for pdp_main: hbm 28%, VALUBusy 26%,
// Occupancy 46% -> latency-bound, not BW/VALU-bound. T_main ~15-16us vs
// 10.6us traffic floor. Fix: x prefetched 2 iterations ahead (covers
// ~900cy HBM latency), wt prefetched 1 iteration ahead (L2 ~250cy hides
// under current row's compute+store). Grid stays 2048 blocks (32 waves/CU).
// Compute path bitwise-unchanged from the validated R5/R6 kernel.

#define IN_F  256
#define NW    40960   // w leading dimension (columns)
#define NSEG  32
#define NNODE 5
#define USED_COLS (NSEG * NNODE)   // 160

typedef float f32x4 __attribute__((ext_vector_type(4)));

__global__ __launch_bounds__(256) void pdp_prep(const float* __restrict__ w,
                                                float* __restrict__ wt) {
    int tid = blockIdx.x * blockDim.x + threadIdx.x;
    if (tid >= USED_COLS * IN_F) return;
    int f = tid / USED_COLS;   // 0..255
    int c = tid % USED_COLS;   // 0..159
    int j = c % NNODE;
    // c_j = 1 / prod_{m!=j}(X_j - X_m),  X = {-1,-0.5,0,0.5,1}
    float cj = (j == 2) ? 4.0f : ((j == 1 || j == 3) ? (-8.0f / 3.0f) : (2.0f / 3.0f));
    wt[c * IN_F + f] = w[(size_t)f * NW + c] * cj;
}

__device__ __forceinline__ float pdp_eval(float xe,
                                          float w0, float w1, float w2,
                                          float w3, float w4) {
    // bitwise == reference: all scalings are exact powers of two
    float idf  = floorf((xe + 1.0f) * 16.0f);
    float xmin = idf * 0.0625f - 1.0f;
    float xin  = (xe - xmin) * 32.0f - 1.0f;

    float t0 = xin + 1.0f;
    float t1 = xin + 0.5f;
    float t2 = xin;
    float t3 = xin - 0.5f;
    float t4 = xin - 1.0f;

    float p1 = t0;
    float p2 = p1 * t1;
    float p3 = p2 * t2;
    float p4 = p3 * t3;
    float s3 = t4;
    float s2 = s3 * t3;
    float s1 = s2 * t2;
    float s0 = s1 * t1;

    float fx = s0 * w0;
    fx = fmaf(p1 * s1, w1, fx);
    fx = fmaf(p2 * s2, w2, fx);
    fx = fmaf(p3 * s3, w3, fx);
    fx = fmaf(p4,      w4, fx);
    return fx;
}

template <bool TR>
__global__ __launch_bounds__(256) void pdp_main(const float* __restrict__ x,
                                                const float* __restrict__ wsrc,
                                                float* __restrict__ out,
                                                int rows) {
    const int lane   = threadIdx.x & 63;
    const int wv     = threadIdx.x >> 6;   // 4 waves/block
    const int f0     = lane << 2;
    const int stride = gridDim.x * 4;

    int b = blockIdx.x * 4 + wv;
    if (b >= rows) return;

    const float* xb   = x + (size_t)b * IN_F + f0;
    const size_t xstep = (size_t)stride * IN_F;

    // weight fetch for a given (wave-uniform) segment
    auto loadw = [&](int sg, f32x4& a0, f32x4& a1, f32x4& a2, f32x4& a3, f32x4& a4) {
        if constexpr (TR) {
            const float* p = wsrc + (size_t)(sg * NNODE) * IN_F + f0;
            a0 = *reinterpret_cast<const f32x4*>(p);
            a1 = *reinterpret_cast<const f32x4*>(p + IN_F);
            a2 = *reinterpret_cast<const f32x4*>(p + 2 * IN_F);
            a3 = *reinterpret_cast<const f32x4*>(p + 3 * IN_F);
            a4 = *reinterpret_cast<const f32x4*>(p + 4 * IN_F);
        } else {
            const float C0 = 2.0f / 3.0f, C1 = -8.0f / 3.0f, C2 = 4.0f;
            float* A[5] = {(float*)&a0, (float*)&a1, (float*)&a2, (float*)&a3, (float*)&a4};
#pragma unroll
            for (int fi = 0; fi < 4; ++fi) {
                const float* p = wsrc + (size_t)(f0 + fi) * NW + sg * NNODE;
                A[0][fi] = p[0] * C0;
                A[1][fi] = p[1] * C1;
                A[2][fi] = p[2] * C2;
                A[3][fi] = p[3] * C1;
                A[4][fi] = p[4] * C0;
            }
        }
    };

    bool v1 = (b + stride)     < rows;   // wave-uniform validity flags
    bool v2 = (b + 2 * stride) < rows;

    // prologue: issue x[b] and x[b+s] together (independent loads)
    f32x4 x_cur = __builtin_nontemporal_load(reinterpret_cast<const f32x4*>(xb));
    f32x4 x_nxt;
    if (v1) x_nxt = __builtin_nontemporal_load(reinterpret_cast<const f32x4*>(xb + xstep));

    // current row's weights
    int seg = (int)floorf((__shfl(x_cur.x, 0) + 1.0f) * 16.0f);
    f32x4 wc0, wc1, wc2, wc3, wc4;
    loadw(seg, wc0, wc1, wc2, wc3, wc4);

    while (true) {
        // stage 1: x two-ahead (slack ~2 iterations >= HBM latency)
        f32x4 x_n2;
        if (v2) x_n2 = __builtin_nontemporal_load(
                    reinterpret_cast<const f32x4*>(xb + 2 * xstep));

        // stage 2: next row's seg + weight issue (L2 latency hides under stage 3)
        int seg_n = 0;
        f32x4 wn0, wn1, wn2, wn3, wn4;
        if (v1) {
            seg_n = (int)floorf((__shfl(x_nxt.x, 0) + 1.0f) * 16.0f);
            loadw(seg_n, wn0, wn1, wn2, wn3, wn4);
        }

        // stage 3: compute + store current row
        f32x4 o;
        o.x = pdp_eval(x_cur.x, wc0.x, wc1.x, wc2.x, wc3.x, wc4.x);
        o.y = pdp_eval(x_cur.y, wc0.y, wc1.y, wc2.y, wc3.y, wc4.y);
        o.z = pdp_eval(x_cur.z, wc0.z, wc1.z, wc2.z, wc3.z, wc4.z);
        o.w = pdp_eval(x_cur.w, wc0.w, wc1.w, wc2.w, wc3.w, wc4.w);
        __builtin_nontemporal_store(
            o, reinterpret_cast<f32x4*>(out + (size_t)b * IN_F + f0));

        if (!v1) break;
        b  += stride;
        xb += xstep;
        x_cur = x_nxt;  x_nxt = x_n2;
        wc0 = wn0; wc1 = wn1; wc2 = wn2; wc3 = wn3; wc4 = wn4;
        v1 = v2;
        v2 = (b + 2 * stride) < rows;
    }
}

extern "C" void kernel_launch(void* const* d_in, const int* in_sizes, int n_in,
                              void* d_out, int out_size, void* d_ws, size_t ws_size,
                              hipStream_t stream) {
    const float* x = (const float*)d_in[0];
    const float* w = (const float*)d_in[1];
    float* out = (float*)d_out;

    const int B = in_sizes[0] / IN_F;   // 32768

    int nblk = (B + 3) / 4;
    if (nblk > 2048) nblk = 2048;       // 8192 waves = 32 waves/CU, 4 rows/wave... -> 4 iters

    const size_t wt_bytes = (size_t)USED_COLS * IN_F * sizeof(float);  // 160 KB
    if (ws_size >= wt_bytes) {
        float* wt = (float*)d_ws;
        const int total = USED_COLS * IN_F;
        pdp_prep<<<(total + 255) / 256, 256, 0, stream>>>(w, wt);
        pdp_main<true><<<nblk, 256, 0, stream>>>(x, wt, out, B);
    } else {
        pdp_main<false><<<nblk, 256, 0, stream>>>(x, w, out, B);
    }
}

// Round 10
// 114.732 us; speedup vs baseline: 1.9117x; 1.0122x over previous
//
#include <hip/hip_runtime.h>

// PiecewiseDiscontinuousPolynomial — R10: regular (L2 write-back) stores
// Evidence trail:
//   R8 (REP=8 diag): main steady-state 14.9us/rep, hbm 28%, VALU 26%,
//     occupancy 46% -> neither pipe saturated. x re-reads L3-absorbed.
//   R6 (1-deep prefetch) -1.6us, R9 (3-stage pipeline) +0us -> prefetch
//     depth is NOT the limiter.
//   Suspect: nt stores bypass L2 -> 1.85 TB/s sustained write, while the
//     harness fill kernel (regular stores) does 6.5 TB/s on the same sizes.
// R10 change: store via regular global_store (L2 write-back), everything
// else identical to the validated R6 kernel. Compute bitwise-unchanged.

#define IN_F  256
#define NW    40960   // w leading dimension (columns)
#define NSEG  32
#define NNODE 5
#define USED_COLS (NSEG * NNODE)   // 160

typedef float f32x4 __attribute__((ext_vector_type(4)));

__global__ __launch_bounds__(256) void pdp_prep(const float* __restrict__ w,
                                                float* __restrict__ wt) {
    int tid = blockIdx.x * blockDim.x + threadIdx.x;
    if (tid >= USED_COLS * IN_F) return;
    int f = tid / USED_COLS;   // 0..255
    int c = tid % USED_COLS;   // 0..159  (reads contiguous in c per f)
    int j = c % NNODE;
    // c_j = 1 / prod_{m!=j}(X_j - X_m),  X = {-1,-0.5,0,0.5,1}
    float cj = (j == 2) ? 4.0f : ((j == 1 || j == 3) ? (-8.0f / 3.0f) : (2.0f / 3.0f));
    wt[c * IN_F + f] = w[(size_t)f * NW + c] * cj;
}

__device__ __forceinline__ float pdp_eval(float xe,
                                          float w0, float w1, float w2,
                                          float w3, float w4) {
    // bitwise == reference: all scalings are exact powers of two
    float idf  = floorf((xe + 1.0f) * 16.0f);        // == floor((x+1)/2*32)
    float xmin = idf * 0.0625f - 1.0f;               // exact
    float xin  = (xe - xmin) * 32.0f - 1.0f;         // exact

    float t0 = xin + 1.0f;
    float t1 = xin + 0.5f;
    float t2 = xin;
    float t3 = xin - 0.5f;
    float t4 = xin - 1.0f;

    // numerators via prefix/suffix products (denominators folded into w)
    float p1 = t0;
    float p2 = p1 * t1;
    float p3 = p2 * t2;
    float p4 = p3 * t3;
    float s3 = t4;
    float s2 = s3 * t3;
    float s1 = s2 * t2;
    float s0 = s1 * t1;

    float fx = s0 * w0;
    fx = fmaf(p1 * s1, w1, fx);
    fx = fmaf(p2 * s2, w2, fx);
    fx = fmaf(p3 * s3, w3, fx);
    fx = fmaf(p4,      w4, fx);
    return fx;
}

template <bool TR>
__global__ __launch_bounds__(256) void pdp_main(const float* __restrict__ x,
                                                const float* __restrict__ wsrc,
                                                float* __restrict__ out,
                                                int rows) {
    const int lane   = threadIdx.x & 63;
    const int wv     = threadIdx.x >> 6;   // 4 waves/block -> 4 rows/iter
    const int f0     = lane << 2;          // this lane's first feature
    const int stride = gridDim.x * 4;

    int b = blockIdx.x * 4 + wv;
    if (b >= rows) return;

    // pipeline prologue: first x load
    f32x4 xv = __builtin_nontemporal_load(
        reinterpret_cast<const f32x4*>(x + (size_t)b * IN_F + f0));

    while (true) {
        // issue next iteration's x load BEFORE consuming xv (uniform branch)
        const int bn = b + stride;
        const bool have_next = bn < rows;
        f32x4 xn;
        if (have_next)
            xn = __builtin_nontemporal_load(
                reinterpret_cast<const f32x4*>(x + (size_t)bn * IN_F + f0));

        // row segment from feature 0 (lane 0 holds it) -- wave-uniform
        float x0  = __shfl(xv.x, 0);
        int   seg = (int)floorf((x0 + 1.0f) * 16.0f);

        float wf[NNODE][4];
        if constexpr (TR) {
            // coalesced: wt[(seg*5+j)*256 + f], prescaled by c_j
            const float* p = wsrc + (size_t)(seg * NNODE) * IN_F + f0;
#pragma unroll
            for (int j = 0; j < NNODE; ++j) {
                f32x4 t = *reinterpret_cast<const f32x4*>(p + j * IN_F);
                wf[j][0] = t.x; wf[j][1] = t.y; wf[j][2] = t.z; wf[j][3] = t.w;
            }
        } else {
            const float C0 = 2.0f / 3.0f, C1 = -8.0f / 3.0f, C2 = 4.0f;
#pragma unroll
            for (int fi = 0; fi < 4; ++fi) {
                const float* p = wsrc + (size_t)(f0 + fi) * NW + seg * NNODE;
                wf[0][fi] = p[0] * C0;
                wf[1][fi] = p[1] * C1;
                wf[2][fi] = p[2] * C2;
                wf[3][fi] = p[3] * C1;
                wf[4][fi] = p[4] * C0;
            }
        }

        f32x4 o;
        o.x = pdp_eval(xv.x, wf[0][0], wf[1][0], wf[2][0], wf[3][0], wf[4][0]);
        o.y = pdp_eval(xv.y, wf[0][1], wf[1][1], wf[2][1], wf[3][1], wf[4][1]);
        o.z = pdp_eval(xv.z, wf[0][2], wf[1][2], wf[2][2], wf[3][2], wf[4][2]);
        o.w = pdp_eval(xv.w, wf[0][3], wf[1][3], wf[2][3], wf[3][3], wf[4][3]);

        // R10: REGULAR store (L2 write-back path) — the one change vs R6
        *reinterpret_cast<f32x4*>(out + (size_t)b * IN_F + f0) = o;

        if (!have_next) break;
        xv = xn;
        b  = bn;
    }
}

extern "C" void kernel_launch(void* const* d_in, const int* in_sizes, int n_in,
                              void* d_out, int out_size, void* d_ws, size_t ws_size,
                              hipStream_t stream) {
    const float* x = (const float*)d_in[0];
    const float* w = (const float*)d_in[1];
    float* out = (float*)d_out;

    const int B = in_sizes[0] / IN_F;   // 32768

    // grid: cap ~2048 blocks, grid-stride over rows (4 rows per block-iter)
    int nblk = (B + 3) / 4;
    if (nblk > 2048) nblk = 2048;

    const size_t wt_bytes = (size_t)USED_COLS * IN_F * sizeof(float);  // 160 KB
    if (ws_size >= wt_bytes) {
        float* wt = (float*)d_ws;
        const int total = USED_COLS * IN_F;
        pdp_prep<<<(total + 255) / 256, 256, 0, stream>>>(w, wt);
        pdp_main<true><<<nblk, 256, 0, stream>>>(x, wt, out, B);
    } else {
        pdp_main<false><<<nblk, 256, 0, stream>>>(x, w, out, B);
    }
}

// Round 11
// 109.214 us; speedup vs baseline: 2.0083x; 1.0505x over previous
//
#include <hip/hip_runtime.h>

// PiecewiseDiscontinuousPolynomial — R11: flat launch, 1 wave = 1 row
// Evidence ledger:
//   R8 REP-diag: main 14.9us/pass, hbm 28%, VALU 26%, occ 46% -> neither
//     pipe saturated; latency/issue-bound. Traffic floor 10.6us.
//   R6 prefetch(-1.6), R9 3-stage(+0), R10 store-path(-0.1): all noise.
//   dur_us =~ 98us fixed harness floor (41us ws-fill + 5us out-fill +
//     21us input restore + launch gaps) + ~17us our kernels.
// R11: remove the grid-stride loop entirely. 8192 blocks x 4 waves, each
// wave handles exactly one row: no loop bookkeeping, no validity flags,
// no prefetch registers. Compute path bitwise-unchanged.

#define IN_F  256
#define NW    40960   // w leading dimension (columns)
#define NSEG  32
#define NNODE 5
#define USED_COLS (NSEG * NNODE)   // 160

typedef float f32x4 __attribute__((ext_vector_type(4)));

__global__ __launch_bounds__(256) void pdp_prep(const float* __restrict__ w,
                                                float* __restrict__ wt) {
    int tid = blockIdx.x * blockDim.x + threadIdx.x;
    if (tid >= USED_COLS * IN_F) return;
    int f = tid / USED_COLS;   // 0..255
    int c = tid % USED_COLS;   // 0..159  (reads contiguous in c per f)
    int j = c % NNODE;
    // c_j = 1 / prod_{m!=j}(X_j - X_m),  X = {-1,-0.5,0,0.5,1}
    float cj = (j == 2) ? 4.0f : ((j == 1 || j == 3) ? (-8.0f / 3.0f) : (2.0f / 3.0f));
    wt[c * IN_F + f] = w[(size_t)f * NW + c] * cj;
}

__device__ __forceinline__ float pdp_eval(float xe,
                                          float w0, float w1, float w2,
                                          float w3, float w4) {
    // bitwise == reference: all scalings are exact powers of two
    float idf  = floorf((xe + 1.0f) * 16.0f);        // == floor((x+1)/2*32)
    float xmin = idf * 0.0625f - 1.0f;               // exact
    float xin  = (xe - xmin) * 32.0f - 1.0f;         // exact

    float t0 = xin + 1.0f;
    float t1 = xin + 0.5f;
    float t2 = xin;
    float t3 = xin - 0.5f;
    float t4 = xin - 1.0f;

    // numerators via prefix/suffix products (denominators folded into w)
    float p1 = t0;
    float p2 = p1 * t1;
    float p3 = p2 * t2;
    float p4 = p3 * t3;
    float s3 = t4;
    float s2 = s3 * t3;
    float s1 = s2 * t2;
    float s0 = s1 * t1;

    float fx = s0 * w0;
    fx = fmaf(p1 * s1, w1, fx);
    fx = fmaf(p2 * s2, w2, fx);
    fx = fmaf(p3 * s3, w3, fx);
    fx = fmaf(p4,      w4, fx);
    return fx;
}

template <bool TR>
__global__ __launch_bounds__(256) void pdp_main(const float* __restrict__ x,
                                                const float* __restrict__ wsrc,
                                                float* __restrict__ out,
                                                int rows) {
    const int lane = threadIdx.x & 63;
    const int wv   = threadIdx.x >> 6;     // 4 waves/block, 1 row each
    const int f0   = lane << 2;            // this lane's first feature
    const int b    = blockIdx.x * 4 + wv;

    if (b >= rows) return;

    const f32x4 xv = *reinterpret_cast<const f32x4*>(x + (size_t)b * IN_F + f0);

    // row segment from feature 0 (lane 0 holds it) -- wave-uniform
    float x0  = __shfl(xv.x, 0);
    int   seg = (int)floorf((x0 + 1.0f) * 16.0f);

    float wf[NNODE][4];
    if constexpr (TR) {
        // coalesced: wt[(seg*5+j)*256 + f], prescaled by c_j (L2-resident)
        const float* p = wsrc + (size_t)(seg * NNODE) * IN_F + f0;
#pragma unroll
        for (int j = 0; j < NNODE; ++j) {
            f32x4 t = *reinterpret_cast<const f32x4*>(p + j * IN_F);
            wf[j][0] = t.x; wf[j][1] = t.y; wf[j][2] = t.z; wf[j][3] = t.w;
        }
    } else {
        const float C0 = 2.0f / 3.0f, C1 = -8.0f / 3.0f, C2 = 4.0f;
#pragma unroll
        for (int fi = 0; fi < 4; ++fi) {
            const float* p = wsrc + (size_t)(f0 + fi) * NW + seg * NNODE;
            wf[0][fi] = p[0] * C0;
            wf[1][fi] = p[1] * C1;
            wf[2][fi] = p[2] * C2;
            wf[3][fi] = p[3] * C1;
            wf[4][fi] = p[4] * C0;
        }
    }

    f32x4 o;
    o.x = pdp_eval(xv.x, wf[0][0], wf[1][0], wf[2][0], wf[3][0], wf[4][0]);
    o.y = pdp_eval(xv.y, wf[0][1], wf[1][1], wf[2][1], wf[3][1], wf[4][1]);
    o.z = pdp_eval(xv.z, wf[0][2], wf[1][2], wf[2][2], wf[3][2], wf[4][2]);
    o.w = pdp_eval(xv.w, wf[0][3], wf[1][3], wf[2][3], wf[3][3], wf[4][3]);

    *reinterpret_cast<f32x4*>(out + (size_t)b * IN_F + f0) = o;
}

extern "C" void kernel_launch(void* const* d_in, const int* in_sizes, int n_in,
                              void* d_out, int out_size, void* d_ws, size_t ws_size,
                              hipStream_t stream) {
    const float* x = (const float*)d_in[0];
    const float* w = (const float*)d_in[1];
    float* out = (float*)d_out;

    const int B = in_sizes[0] / IN_F;   // 32768

    // flat: 1 wave per row, 4 waves per block -> B/4 blocks (8192)
    int nblk = (B + 3) / 4;

    const size_t wt_bytes = (size_t)USED_COLS * IN_F * sizeof(float);  // 160 KB
    if (ws_size >= wt_bytes) {
        float* wt = (float*)d_ws;
        const int total = USED_COLS * IN_F;
        pdp_prep<<<(total + 255) / 256, 256, 0, stream>>>(w, wt);
        pdp_main<true><<<nblk, 256, 0, stream>>>(x, wt, out, B);
    } else {
        pdp_main<false><<<nblk, 256, 0, stream>>>(x, w, out, B);
    }
}